// Round 1
// baseline (430.442 us; speedup 1.0000x reference)
//
#include <hip/hip_runtime.h>
#include <cstdint>
#include <cstddef>

// Problem constants (from reference setup_inputs)
constexpr int P  = 200000;   // points
constexpr int C  = 256;      // clicks
constexpr int NC = 200;      // classes
#define DICE_TH 0.4f
#define CLS_TH  0.5f
#define LN_EPS  1e-5f

// gram split-K config: KC * NCHUNK == P, KC % 32 == 0
constexpr int KC = 1600;
constexpr int NCHUNK = 125;

// workspace byte offsets (total < 700 KB)
constexpr size_t WS_G       = 0;        // 256*256*4 = 262144
constexpr size_t WS_S       = 262144;   // 256*4
constexpr size_t WS_PROW    = 263168;   // 256*200*4 = 204800
constexpr size_t WS_PT      = 467968;   // 200*256*4 = 204800
constexpr size_t WS_COND    = 672768;   // 256*4*8 = 8192
constexpr size_t WS_MSTART  = 680960;   // 257*4
constexpr size_t WS_MEMBERS = 682240;   // 256*4

typedef float floatx4 __attribute__((ext_vector_type(4)));
typedef float floatx16 __attribute__((ext_vector_type(16)));
typedef __bf16 bf16x4 __attribute__((ext_vector_type(4)));
typedef __bf16 bf16x8 __attribute__((ext_vector_type(8)));
typedef unsigned short ushort4v __attribute__((ext_vector_type(4)));
typedef unsigned short ushort8 __attribute__((ext_vector_type(8)));

// ---------------------------------------------------------------------------
// Kernel 1: G = M^T M via bf16 MFMA (fp32 accumulate), split-K atomicAdd.
// Symmetric: only tiles (0,0),(0,1),(1,1) computed; cond reads mirror for
// the (1,0) quadrant. Column sums s fused (LDS-reduced, then 1 atomic/col).
//
// Staging (new): row-wise dwordx4 loads (4/thread/step instead of 16 scalar
// dwords), packed bf16 convert (v_cvt_pk_bf16_f32 via __builtin_convertvector),
// in-register 4x4 transpose, ds_write_b64 to [col][k] LDS with an even-XOR
// granule swizzle: granule kq of column col stored at position
// kq ^ (((col>>2)&3)<<1). XOR with an even value keeps b128-readable granule
// pairs adjacent and in k order; spreads write banks 8-way -> 4-way.
// ---------------------------------------------------------------------------
constexpr int LDA = 40;   // ushort leading dim per column (32 k + 8 pad)

__global__ __launch_bounds__(256, 2) void gram_mfma_kernel(
    const float* __restrict__ M, float* __restrict__ G, float* __restrict__ s) {
  __shared__ unsigned short Abf[128 * LDA];
  __shared__ unsigned short Bbf[128 * LDA];
  __shared__ float scol[128];

  const int type = blockIdx.x;              // 0:(0,0) 1:(0,128) 2:(128,128)
  const int i0 = (type == 2) ? 128 : 0;
  const int j0 = (type == 0) ? 0 : 128;
  const bool diag = (type != 1);
  const int tid = threadIdx.x;
  const int wv = tid >> 6, lane = tid & 63;
  const int g  = tid & 31;                  // column group (4 cols)
  const int kq = tid >> 5;                  // k-quad in [0,8) (4 ks)
  const int k0 = blockIdx.y * KC;
  const int swz = (g & 3) << 1;             // even XOR for write position

  if (tid < 128) scol[tid] = 0.f;

  floatx16 acc[4];
#pragma unroll
  for (int t = 0; t < 4; ++t)
#pragma unroll
    for (int r = 0; r < 16; ++r) acc[t][r] = 0.f;
  float ss[4] = {0.f, 0.f, 0.f, 0.f};

  // MFMA frag addresses (lane-fixed parts)
  const int mrow = lane & 31;
  const int kgrp = (lane >> 5) * 8;
  const int xa = ((mrow >> 2) & 3) << 1;    // read-side XOR (row-local = col)
  const int wbase = (kq ^ swz) << 2;        // swizzled ushort offset for writes

  for (int step = 0; step < KC / 32; ++step) {
    const int kb = k0 + step * 32 + 4 * kq;
    {
      // A slice: rows kb..kb+3, cols i0+4g..i0+4g+3 (dwordx4 each row)
      const float* src = M + (size_t)kb * 256 + i0 + 4 * g;
      floatx4 r0 = *reinterpret_cast<const floatx4*>(src);
      floatx4 r1 = *reinterpret_cast<const floatx4*>(src + 256);
      floatx4 r2 = *reinterpret_cast<const floatx4*>(src + 512);
      floatx4 r3 = *reinterpret_cast<const floatx4*>(src + 768);
      if (diag) {
        ss[0] += r0[0] + r1[0] + r2[0] + r3[0];
        ss[1] += r0[1] + r1[1] + r2[1] + r3[1];
        ss[2] += r0[2] + r1[2] + r2[2] + r3[2];
        ss[3] += r0[3] + r1[3] + r2[3] + r3[3];
      }
#pragma unroll
      for (int cc = 0; cc < 4; ++cc) {
        floatx4 f = {r0[cc], r1[cc], r2[cc], r3[cc]};   // 4 ks of one col
        bf16x4 b = __builtin_convertvector(f, bf16x4);   // 2x v_cvt_pk_bf16_f32
        *reinterpret_cast<ushort4v*>(&Abf[(4 * g + cc) * LDA + wbase]) =
            __builtin_bit_cast(ushort4v, b);
      }
    }
    if (!diag) {
      // B slice: cols j0+4g..j0+4g+3
      const float* src = M + (size_t)kb * 256 + j0 + 4 * g;
      floatx4 r0 = *reinterpret_cast<const floatx4*>(src);
      floatx4 r1 = *reinterpret_cast<const floatx4*>(src + 256);
      floatx4 r2 = *reinterpret_cast<const floatx4*>(src + 512);
      floatx4 r3 = *reinterpret_cast<const floatx4*>(src + 768);
#pragma unroll
      for (int cc = 0; cc < 4; ++cc) {
        floatx4 f = {r0[cc], r1[cc], r2[cc], r3[cc]};
        bf16x4 b = __builtin_convertvector(f, bf16x4);
        *reinterpret_cast<ushort4v*>(&Bbf[(4 * g + cc) * LDA + wbase]) =
            __builtin_bit_cast(ushort4v, b);
      }
    }
    __syncthreads();

    const unsigned short* Bsrc = diag ? Abf : Bbf;
#pragma unroll
    for (int sub = 0; sub < 2; ++sub) {
      const int ko = sub * 16 + kgrp;                  // {0,8,16,24}
      const int koff = (((ko >> 2) ^ xa) << 2);        // swizzled, b128-aligned
      bf16x8 a = __builtin_bit_cast(
          bf16x8, *reinterpret_cast<const ushort8*>(
                      &Abf[(32 * wv + mrow) * LDA + koff]));
#pragma unroll
      for (int t = 0; t < 4; ++t) {
        bf16x8 b = __builtin_bit_cast(
            bf16x8, *reinterpret_cast<const ushort8*>(
                        &Bsrc[(32 * t + mrow) * LDA + koff]));
        acc[t] = __builtin_amdgcn_mfma_f32_32x32x16_bf16(a, b, acc[t], 0, 0, 0);
      }
    }
    __syncthreads();
  }

  // epilogue: C/D layout col=lane&31, row=(r&3)+8*(r>>2)+4*(lane>>5)
#pragma unroll
  for (int t = 0; t < 4; ++t) {
    const int gc = j0 + 32 * t + (lane & 31);
#pragma unroll
    for (int r = 0; r < 16; ++r) {
      const int gr = i0 + 32 * wv + (r & 3) + 8 * (r >> 2) + 4 * (lane >> 5);
      atomicAdd(&G[(size_t)gr * 256 + gc], acc[t][r]);
    }
  }
  if (diag) {
#pragma unroll
    for (int cc = 0; cc < 4; ++cc) atomicAdd(&scol[4 * g + cc], ss[cc]);
    __syncthreads();
    if (tid < 128) atomicAdd(&s[i0 + tid], scol[tid]);
  }
}

// ---------------------------------------------------------------------------
// Kernel 2: layernorm of cls_logits -> p (row-major) and pT (transposed)
// ---------------------------------------------------------------------------
__global__ __launch_bounds__(64) void ln_kernel(const float* __restrict__ cls,
                                                float* __restrict__ p_row,
                                                float* __restrict__ pT) {
  const int c = blockIdx.x;
  const int t = threadIdx.x;
  const float* x = cls + (size_t)c * NC;
  float v0 = x[t];
  float v1 = x[t + 64];
  float v2 = (t < 72) ? x[t + 128] : 0.f;

  float sum = v0 + v1 + v2;
#pragma unroll
  for (int o = 32; o > 0; o >>= 1) sum += __shfl_xor(sum, o);
  const float mu = sum / (float)NC;

  float d0 = v0 - mu, d1 = v1 - mu, d2 = (t < 72) ? (v2 - mu) : 0.f;
  float sq = d0 * d0 + d1 * d1 + d2 * d2;
#pragma unroll
  for (int o = 32; o > 0; o >>= 1) sq += __shfl_xor(sq, o);
  const float var = sq / (float)NC;
  const float inv = 1.0f / sqrtf(var + LN_EPS);

  float p0 = d0 * inv, p1 = d1 * inv, p2 = d2 * inv;
  p_row[(size_t)c * NC + t] = p0;
  p_row[(size_t)c * NC + t + 64] = p1;
  pT[(size_t)t * C + c] = p0;
  pT[(size_t)(t + 64) * C + c] = p1;
  if (t < 72) {
    p_row[(size_t)c * NC + t + 128] = p2;
    pT[(size_t)(t + 128) * C + c] = p2;
  }
}

// ---------------------------------------------------------------------------
// Kernel 3: cond[i][j] = (dice > 0.4) && (sim > 0.5), packed 4x u64 per row.
// G's (i>=128, j<128) quadrant was not written (symmetry) -> read mirror.
// ---------------------------------------------------------------------------
__global__ __launch_bounds__(256) void cond_kernel(
    const float* __restrict__ G, const float* __restrict__ s,
    const float* __restrict__ p_row, const float* __restrict__ pT,
    unsigned long long* __restrict__ condW) {
  __shared__ float pi[NC];
  const int i = blockIdx.x;
  const int j = threadIdx.x;
  if (j < NC) pi[j] = p_row[(size_t)i * NC + j];
  __syncthreads();

  const float si = s[i];
  const float sj = s[j];
  const float g = (i >= 128 && j < 128) ? G[(size_t)j * C + i]
                                        : G[(size_t)i * C + j];
  const float dice = 2.f * g / (si + sj);

  float acc = 0.f;
#pragma unroll 8
  for (int k = 0; k < NC; ++k) acc = fmaf(pi[k], pT[(size_t)k * C + j], acc);

  const bool cnd = (dice > DICE_TH) && (acc > CLS_TH);
  unsigned long long m = __ballot(cnd);
  if ((j & 63) == 0) condW[i * 4 + (j >> 6)] = m;
}

// ---------------------------------------------------------------------------
// Kernel 4: sequential greedy scan (exact reference semantics), single wave.
// ---------------------------------------------------------------------------
__global__ __launch_bounds__(64) void scan_kernel(
    const unsigned long long* __restrict__ condW,
    float* __restrict__ out_labels, float* __restrict__ out_valid,
    int* __restrict__ mstart, int* __restrict__ members) {
  __shared__ unsigned long long cS[C * 4];
  __shared__ int cnt[C];
  __shared__ int ms[C + 1];
  const int t = threadIdx.x;

  for (int idx = t; idx < C * 4; idx += 64) cS[idx] = condW[idx];
  for (int idx = t; idx < C; idx += 64) cnt[idx] = 0;
  __syncthreads();

  unsigned long long asg[4] = {0ull, 0ull, 0ull, 0ull};
  int lab[4] = {-1, -1, -1, -1};   // lab[w] is label of column w*64 + t

#pragma unroll
  for (int w = 0; w < 4; ++w) {
    for (int b = 0; b < 64; ++b) {
      const int i = w * 64 + b;
      if (!((asg[w] >> b) & 1ull)) {   // leader i: take unassigned matches
#pragma unroll
        for (int w2 = 0; w2 < 4; ++w2) {
          unsigned long long tk = cS[i * 4 + w2] & ~asg[w2];
          asg[w2] |= tk;
          if ((tk >> t) & 1ull) lab[w2] = i;
        }
      }
    }
  }

  // counts per leader
#pragma unroll
  for (int w = 0; w < 4; ++w)
    if (lab[w] >= 0) atomicAdd(&cnt[lab[w]], 1);
  __syncthreads();

  if (t == 0) {
    ms[0] = 0;
    for (int c2 = 0; c2 < C; ++c2) ms[c2 + 1] = ms[c2] + cnt[c2];
  }
  __syncthreads();
  for (int idx = t; idx < C; idx += 64) cnt[idx] = ms[idx];
  __syncthreads();
#pragma unroll
  for (int w = 0; w < 4; ++w) {
    if (lab[w] >= 0) {
      int pos = atomicAdd(&cnt[lab[w]], 1);
      members[pos] = w * 64 + t;
    }
  }
#pragma unroll
  for (int w = 0; w < 4; ++w) {
    const int col = w * 64 + t;
    out_labels[col] = (float)lab[w];
    out_valid[col] = (ms[col + 1] > ms[col]) ? 1.0f : 0.0f;
  }
  for (int idx = t; idx < C + 1; idx += 64) mstart[idx] = ms[idx];
}

// ---------------------------------------------------------------------------
// Kernel 5: new_masks[p][c] = valid(c) ? max over members of M[p][j] : 0
// Compute thread-per-col (as before), then transpose through LDS and store
// dwordx4 nontemporal (don't evict L3-resident M with streaming writes).
// ---------------------------------------------------------------------------
__global__ __launch_bounds__(256) void merge_masks_kernel(
    const float* __restrict__ M, const int* __restrict__ mstart,
    const int* __restrict__ members, float* __restrict__ out_masks) {
  __shared__ float rows[8 * 256];
  __shared__ int msS[C + 1];
  __shared__ int memS[C];
  const int tid = threadIdx.x;
  const size_t p0 = (size_t)blockIdx.x * 8;

  msS[tid] = mstart[tid];
  if (tid == 0) msS[C] = mstart[C];
  memS[tid] = members[tid];

  const float4* src = reinterpret_cast<const float4*>(M + p0 * 256);
#pragma unroll
  for (int it = 0; it < 2; ++it)
    reinterpret_cast<float4*>(rows)[it * 256 + tid] = src[it * 256 + tid];
  __syncthreads();

  const int st = msS[tid], en = msS[tid + 1];
  float mx[8];
  if (en > st) {
    const int m0 = memS[st];
#pragma unroll
    for (int r = 0; r < 8; ++r) mx[r] = rows[r * 256 + m0];
    for (int k = st + 1; k < en; ++k) {
      const int mm = memS[k];
#pragma unroll
      for (int r = 0; r < 8; ++r) mx[r] = fmaxf(mx[r], rows[r * 256 + mm]);
    }
  } else {
#pragma unroll
    for (int r = 0; r < 8; ++r) mx[r] = 0.f;
  }
  __syncthreads();                 // all reads of rows done; reuse as out stage
#pragma unroll
  for (int r = 0; r < 8; ++r) rows[r * 256 + tid] = mx[r];
  __syncthreads();

  const int r2 = tid >> 6;
  const int cg = (tid & 63) << 2;
#pragma unroll
  for (int pass = 0; pass < 2; ++pass) {
    const int rr = pass * 4 + r2;
    floatx4 v = *reinterpret_cast<const floatx4*>(&rows[rr * 256 + cg]);
    __builtin_nontemporal_store(
        v, reinterpret_cast<floatx4*>(&out_masks[(p0 + rr) * 256 + cg]));
  }
}

// ---------------------------------------------------------------------------
// Kernel 6: new_cls[c][k] = valid(c) ? max over members of cls[j][k] : 0
// ---------------------------------------------------------------------------
__global__ __launch_bounds__(256) void merge_cls_kernel(
    const float* __restrict__ cls, const int* __restrict__ mstart,
    const int* __restrict__ members, float* __restrict__ out_cls) {
  __shared__ int se[2];
  const int c = blockIdx.x;
  const int t = threadIdx.x;
  if (t < 2) se[t] = mstart[c + t];
  __syncthreads();
  const int st = se[0], en = se[1];
  if (t < NC) {
    float mx = 0.f;
    if (en > st) {
      mx = cls[(size_t)members[st] * NC + t];
      for (int k = st + 1; k < en; ++k)
        mx = fmaxf(mx, cls[(size_t)members[k] * NC + t]);
    }
    out_cls[(size_t)c * NC + t] = mx;
  }
}

// ---------------------------------------------------------------------------
extern "C" void kernel_launch(void* const* d_in, const int* in_sizes, int n_in,
                              void* d_out, int out_size, void* d_ws,
                              size_t ws_size, hipStream_t stream) {
  const float* M = (const float*)d_in[0];    // [P, C] fp32
  const float* cls = (const float*)d_in[1];  // [C, NC] fp32

  float* out = (float*)d_out;
  char* ws = (char*)d_ws;
  float* G = (float*)(ws + WS_G);
  float* s = (float*)(ws + WS_S);
  float* p_row = (float*)(ws + WS_PROW);
  float* pT = (float*)(ws + WS_PT);
  unsigned long long* condW = (unsigned long long*)(ws + WS_COND);
  int* mstart = (int*)(ws + WS_MSTART);
  int* members = (int*)(ws + WS_MEMBERS);

  float* out_labels = out;
  float* out_valid = out + 256;
  float* out_masks = out + 512;
  float* out_cls = out + 512 + (size_t)P * 256;

  // zero accumulators (G and s are contiguous at ws start)
  hipMemsetAsync(ws, 0, WS_S + 1024, stream);

  gram_mfma_kernel<<<dim3(3, NCHUNK), 256, 0, stream>>>(M, G, s);
  ln_kernel<<<C, 64, 0, stream>>>(cls, p_row, pT);
  cond_kernel<<<C, 256, 0, stream>>>(G, s, p_row, pT, condW);
  scan_kernel<<<1, 64, 0, stream>>>(condW, out_labels, out_valid, mstart,
                                    members);
  merge_masks_kernel<<<P / 8, 256, 0, stream>>>(M, mstart, members, out_masks);
  merge_cls_kernel<<<C, 256, 0, stream>>>(cls, mstart, members, out_cls);
}

// Round 2
// 417.554 us; speedup vs baseline: 1.0309x; 1.0309x over previous
//
#include <hip/hip_runtime.h>
#include <cstdint>
#include <cstddef>

// Problem constants (from reference setup_inputs)
constexpr int P  = 200000;   // points
constexpr int C  = 256;      // clicks
constexpr int NC = 200;      // classes
#define DICE_TH 0.4f
#define CLS_TH  0.5f
#define LN_EPS  1e-5f

// gram split-K config: KC * NCHUNK == P, KC % 32 == 0
constexpr int KC = 1600;
constexpr int NCHUNK = 125;
constexpr int NSTEP = KC / 32;   // 50

// workspace byte offsets
constexpr size_t WS_G       = 0;        // 256*256*4 = 262144
constexpr size_t WS_S       = 262144;   // 256*4
constexpr size_t WS_PROW    = 263168;   // 256*200*4 = 204800
constexpr size_t WS_PT      = 467968;   // 200*256*4 = 204800
constexpr size_t WS_COND    = 672768;   // 256*4*8 = 8192
constexpr size_t WS_MSTART  = 680960;   // 257*4
constexpr size_t WS_MEMBERS = 682240;   // 256*4
constexpr size_t WS_PART    = 1048576;  // partial G tiles (big-ws path)
constexpr size_t PART_BYTES = (size_t)NCHUNK * 3 * 16384 * 4;  // 24.576 MB

typedef float floatx4 __attribute__((ext_vector_type(4)));
typedef float floatx16 __attribute__((ext_vector_type(16)));
typedef __bf16 bf16x4 __attribute__((ext_vector_type(4)));
typedef __bf16 bf16x8 __attribute__((ext_vector_type(8)));
typedef unsigned short ushort4v __attribute__((ext_vector_type(4)));
typedef unsigned short ushort8 __attribute__((ext_vector_type(8)));

// ---------------------------------------------------------------------------
// Kernel 1: G = M^T M via bf16 MFMA (fp32 accumulate), split-K.
// Tiles: (0,0),(0,1),(1,1); cond reads mirror for (1,0).
// Epilogue: big-ws path -> plain stores to per-chunk partial tiles (no
// atomics; reduce_g sums them). Fallback -> atomicAdd into G (old path).
// Wave tiling 64x64 (2a+2b frags per 4 MFMA). T14: next step's global
// loads issued before the MFMA phase (a0/a1 ping-pong, static indexing).
// LDS: [col][k] bf16, LDA=40; write pos kq^(((col>>2)&3)<<1) even-XOR.
// ---------------------------------------------------------------------------
constexpr int LDA = 40;

__global__ __launch_bounds__(256, 2) void gram_mfma_kernel(
    const float* __restrict__ M, float* __restrict__ G, float* __restrict__ s,
    float* __restrict__ part) {
  __shared__ unsigned short Abf[128 * LDA];
  __shared__ unsigned short Bbf[128 * LDA];
  __shared__ float scol[128];

  const int type = blockIdx.x;              // 0:(0,0) 1:(0,128) 2:(128,128)
  const int i0 = (type == 2) ? 128 : 0;
  const int j0 = (type == 0) ? 0 : 128;
  const bool diag = (type != 1);
  const int tid = threadIdx.x;
  const int wv = tid >> 6, lane = tid & 63;
  const int wr = wv >> 1, wc = wv & 1;      // wave -> 64x64 sub-tile
  const int g  = tid & 31;                  // column group (4 cols)
  const int kq = tid >> 5;                  // k-quad in [0,8)
  const int chunk = blockIdx.y;
  const int k0 = chunk * KC;

  if (tid < 128) scol[tid] = 0.f;

  floatx16 acc[4];
#pragma unroll
  for (int t = 0; t < 4; ++t)
#pragma unroll
    for (int r = 0; r < 16; ++r) acc[t][r] = 0.f;
  float ss[4] = {0.f, 0.f, 0.f, 0.f};

  const int mrow = lane & 31;
  const int kgrp = (lane >> 5) * 8;
  const int xa = ((mrow >> 2) & 3) << 1;    // read-side XOR
  const int wbase = (kq ^ ((g & 3) << 1)) << 2;  // swizzled write offset

  const float* baseA = M + i0 + 4 * g;
  const float* baseB = M + j0 + 4 * g;

#define LOADS(dst, base, step_)                                              \
  {                                                                          \
    const float* src_ = (base) + (size_t)(k0 + (step_) * 32 + 4 * kq) * 256; \
    dst[0] = *reinterpret_cast<const floatx4*>(src_);                        \
    dst[1] = *reinterpret_cast<const floatx4*>(src_ + 256);                  \
    dst[2] = *reinterpret_cast<const floatx4*>(src_ + 512);                  \
    dst[3] = *reinterpret_cast<const floatx4*>(src_ + 768);                  \
  }

#define STAGE(dstLds, r_)                                                    \
  {                                                                          \
    _Pragma("unroll") for (int cc = 0; cc < 4; ++cc) {                       \
      floatx4 f = {r_[0][cc], r_[1][cc], r_[2][cc], r_[3][cc]};              \
      bf16x4 b = __builtin_convertvector(f, bf16x4);                         \
      *reinterpret_cast<ushort4v*>(&dstLds[(4 * g + cc) * LDA + wbase]) =    \
          __builtin_bit_cast(ushort4v, b);                                   \
    }                                                                        \
  }

#define SSUM(r_)                                                             \
  if (diag) {                                                                \
    ss[0] += r_[0][0] + r_[1][0] + r_[2][0] + r_[3][0];                      \
    ss[1] += r_[0][1] + r_[1][1] + r_[2][1] + r_[3][1];                      \
    ss[2] += r_[0][2] + r_[1][2] + r_[2][2] + r_[3][2];                      \
    ss[3] += r_[0][3] + r_[1][3] + r_[2][3] + r_[3][3];                      \
  }

#define MFMA_STEP()                                                          \
  {                                                                          \
    const unsigned short* Bsrc = diag ? Abf : Bbf;                           \
    _Pragma("unroll") for (int sub = 0; sub < 2; ++sub) {                    \
      const int ko = sub * 16 + kgrp;                                        \
      const int koff = (((ko >> 2) ^ xa) << 2);                              \
      bf16x8 av0 = __builtin_bit_cast(                                       \
          bf16x8, *reinterpret_cast<const ushort8*>(                         \
                      &Abf[(64 * wr + mrow) * LDA + koff]));                 \
      bf16x8 av1 = __builtin_bit_cast(                                       \
          bf16x8, *reinterpret_cast<const ushort8*>(                         \
                      &Abf[(64 * wr + 32 + mrow) * LDA + koff]));            \
      bf16x8 bv0 = __builtin_bit_cast(                                       \
          bf16x8, *reinterpret_cast<const ushort8*>(                         \
                      &Bsrc[(64 * wc + mrow) * LDA + koff]));                \
      bf16x8 bv1 = __builtin_bit_cast(                                       \
          bf16x8, *reinterpret_cast<const ushort8*>(                         \
                      &Bsrc[(64 * wc + 32 + mrow) * LDA + koff]));           \
      acc[0] = __builtin_amdgcn_mfma_f32_32x32x16_bf16(av0, bv0, acc[0], 0, 0, 0); \
      acc[1] = __builtin_amdgcn_mfma_f32_32x32x16_bf16(av0, bv1, acc[1], 0, 0, 0); \
      acc[2] = __builtin_amdgcn_mfma_f32_32x32x16_bf16(av1, bv0, acc[2], 0, 0, 0); \
      acc[3] = __builtin_amdgcn_mfma_f32_32x32x16_bf16(av1, bv1, acc[3], 0, 0, 0); \
    }                                                                        \
  }

  floatx4 a0[4], a1[4], b0[4], b1[4];
  LOADS(a0, baseA, 0);
  if (!diag) LOADS(b0, baseB, 0);

  for (int sp = 0; sp < NSTEP; sp += 2) {
    SSUM(a0);
    STAGE(Abf, a0);
    if (!diag) STAGE(Bbf, b0);
    __syncthreads();
    // T14: issue next loads; they fly under the MFMA phase
    LOADS(a1, baseA, sp + 1);
    if (!diag) LOADS(b1, baseB, sp + 1);
    MFMA_STEP();
    __syncthreads();

    SSUM(a1);
    STAGE(Abf, a1);
    if (!diag) STAGE(Bbf, b1);
    __syncthreads();
    if (sp + 2 < NSTEP) {
      LOADS(a0, baseA, sp + 2);
      if (!diag) LOADS(b0, baseB, sp + 2);
    }
    MFMA_STEP();
    __syncthreads();
  }
#undef LOADS
#undef STAGE
#undef SSUM
#undef MFMA_STEP

  // epilogue: C/D layout col=lane&31, row=(r&3)+8*(r>>2)+4*(lane>>5)
  if (part != nullptr) {
    float* Pp = part + ((size_t)chunk * 3 + type) * 16384;
#pragma unroll
    for (int ai = 0; ai < 2; ++ai)
#pragma unroll
      for (int bj = 0; bj < 2; ++bj)
#pragma unroll
        for (int r = 0; r < 16; ++r) {
          const int lr = 64 * wr + 32 * ai + (r & 3) + 8 * (r >> 2) + 4 * (lane >> 5);
          const int lc = 64 * wc + 32 * bj + (lane & 31);
          Pp[lr * 128 + lc] = acc[ai * 2 + bj][r];
        }
  } else {
#pragma unroll
    for (int ai = 0; ai < 2; ++ai)
#pragma unroll
      for (int bj = 0; bj < 2; ++bj)
#pragma unroll
        for (int r = 0; r < 16; ++r) {
          const int gr = i0 + 64 * wr + 32 * ai + (r & 3) + 8 * (r >> 2) + 4 * (lane >> 5);
          const int gc = j0 + 64 * wc + 32 * bj + (lane & 31);
          atomicAdd(&G[(size_t)gr * 256 + gc], acc[ai * 2 + bj][r]);
        }
  }
  if (diag) {
#pragma unroll
    for (int cc = 0; cc < 4; ++cc) atomicAdd(&scol[4 * g + cc], ss[cc]);
    __syncthreads();
    if (tid < 128) atomicAdd(&s[i0 + tid], scol[tid]);
  }
}

// ---------------------------------------------------------------------------
// Kernel 1b (big-ws path): G[quadrant] = sum over chunks of partial tiles.
// ---------------------------------------------------------------------------
__global__ __launch_bounds__(128) void reduce_g_kernel(
    const float* __restrict__ part, float* __restrict__ G) {
  const int slot = blockIdx.x >> 7;   // 0..2
  const int lr = blockIdx.x & 127;
  const int lc = threadIdx.x;
  const float* src = part + (size_t)slot * 16384 + (size_t)lr * 128 + lc;
  float s0 = 0.f, s1 = 0.f, s2 = 0.f, s3 = 0.f, s4 = 0.f;
  int ch = 0;
  for (; ch + 5 <= NCHUNK; ch += 5) {
    s0 += src[(size_t)(ch + 0) * 49152];
    s1 += src[(size_t)(ch + 1) * 49152];
    s2 += src[(size_t)(ch + 2) * 49152];
    s3 += src[(size_t)(ch + 3) * 49152];
    s4 += src[(size_t)(ch + 4) * 49152];
  }
  for (; ch < NCHUNK; ++ch) s0 += src[(size_t)ch * 49152];
  const int i0 = (slot == 2) ? 128 : 0;
  const int j0 = (slot == 0) ? 0 : 128;
  G[(size_t)(i0 + lr) * 256 + (j0 + lc)] = ((s0 + s1) + (s2 + s3)) + s4;
}

// ---------------------------------------------------------------------------
// Kernel 2: layernorm of cls_logits -> p (row-major) and pT (transposed)
// ---------------------------------------------------------------------------
__global__ __launch_bounds__(64) void ln_kernel(const float* __restrict__ cls,
                                                float* __restrict__ p_row,
                                                float* __restrict__ pT) {
  const int c = blockIdx.x;
  const int t = threadIdx.x;
  const float* x = cls + (size_t)c * NC;
  float v0 = x[t];
  float v1 = x[t + 64];
  float v2 = (t < 72) ? x[t + 128] : 0.f;

  float sum = v0 + v1 + v2;
#pragma unroll
  for (int o = 32; o > 0; o >>= 1) sum += __shfl_xor(sum, o);
  const float mu = sum / (float)NC;

  float d0 = v0 - mu, d1 = v1 - mu, d2 = (t < 72) ? (v2 - mu) : 0.f;
  float sq = d0 * d0 + d1 * d1 + d2 * d2;
#pragma unroll
  for (int o = 32; o > 0; o >>= 1) sq += __shfl_xor(sq, o);
  const float var = sq / (float)NC;
  const float inv = 1.0f / sqrtf(var + LN_EPS);

  float p0 = d0 * inv, p1 = d1 * inv, p2 = d2 * inv;
  p_row[(size_t)c * NC + t] = p0;
  p_row[(size_t)c * NC + t + 64] = p1;
  pT[(size_t)t * C + c] = p0;
  pT[(size_t)(t + 64) * C + c] = p1;
  if (t < 72) {
    p_row[(size_t)c * NC + t + 128] = p2;
    pT[(size_t)(t + 128) * C + c] = p2;
  }
}

// ---------------------------------------------------------------------------
// Kernel 3: cond[i][j] = (dice > 0.4) && (sim > 0.5), packed 4x u64 per row.
// (1,0) quadrant reads mirror (valid in both ws paths).
// ---------------------------------------------------------------------------
__global__ __launch_bounds__(256) void cond_kernel(
    const float* __restrict__ G, const float* __restrict__ s,
    const float* __restrict__ p_row, const float* __restrict__ pT,
    unsigned long long* __restrict__ condW) {
  __shared__ float pi[NC];
  const int i = blockIdx.x;
  const int j = threadIdx.x;
  if (j < NC) pi[j] = p_row[(size_t)i * NC + j];
  __syncthreads();

  const float si = s[i];
  const float sj = s[j];
  const float g = (i >= 128 && j < 128) ? G[(size_t)j * C + i]
                                        : G[(size_t)i * C + j];
  const float dice = 2.f * g / (si + sj);

  float acc = 0.f;
#pragma unroll 8
  for (int k = 0; k < NC; ++k) acc = fmaf(pi[k], pT[(size_t)k * C + j], acc);

  const bool cnd = (dice > DICE_TH) && (acc > CLS_TH);
  unsigned long long m = __ballot(cnd);
  if ((j & 63) == 0) condW[i * 4 + (j >> 6)] = m;
}

// ---------------------------------------------------------------------------
// Kernel 4: sequential greedy scan (exact reference semantics), single wave.
// ---------------------------------------------------------------------------
__global__ __launch_bounds__(64) void scan_kernel(
    const unsigned long long* __restrict__ condW,
    float* __restrict__ out_labels, float* __restrict__ out_valid,
    int* __restrict__ mstart, int* __restrict__ members) {
  __shared__ unsigned long long cS[C * 4];
  __shared__ int cnt[C];
  __shared__ int ms[C + 1];
  const int t = threadIdx.x;

  for (int idx = t; idx < C * 4; idx += 64) cS[idx] = condW[idx];
  for (int idx = t; idx < C; idx += 64) cnt[idx] = 0;
  __syncthreads();

  unsigned long long asg[4] = {0ull, 0ull, 0ull, 0ull};
  int lab[4] = {-1, -1, -1, -1};   // lab[w] is label of column w*64 + t

#pragma unroll
  for (int w = 0; w < 4; ++w) {
    for (int b = 0; b < 64; ++b) {
      const int i = w * 64 + b;
      if (!((asg[w] >> b) & 1ull)) {   // leader i: take unassigned matches
#pragma unroll
        for (int w2 = 0; w2 < 4; ++w2) {
          unsigned long long tk = cS[i * 4 + w2] & ~asg[w2];
          asg[w2] |= tk;
          if ((tk >> t) & 1ull) lab[w2] = i;
        }
      }
    }
  }

  // counts per leader
#pragma unroll
  for (int w = 0; w < 4; ++w)
    if (lab[w] >= 0) atomicAdd(&cnt[lab[w]], 1);
  __syncthreads();

  if (t == 0) {
    ms[0] = 0;
    for (int c2 = 0; c2 < C; ++c2) ms[c2 + 1] = ms[c2] + cnt[c2];
  }
  __syncthreads();
  for (int idx = t; idx < C; idx += 64) cnt[idx] = ms[idx];
  __syncthreads();
#pragma unroll
  for (int w = 0; w < 4; ++w) {
    if (lab[w] >= 0) {
      int pos = atomicAdd(&cnt[lab[w]], 1);
      members[pos] = w * 64 + t;
    }
  }
#pragma unroll
  for (int w = 0; w < 4; ++w) {
    const int col = w * 64 + t;
    out_labels[col] = (float)lab[w];
    out_valid[col] = (ms[col + 1] > ms[col]) ? 1.0f : 0.0f;
  }
  for (int idx = t; idx < C + 1; idx += 64) mstart[idx] = ms[idx];
}

// ---------------------------------------------------------------------------
// Kernel 5: new_masks[p][c] = valid(c) ? max over members of M[p][j] : 0
// ---------------------------------------------------------------------------
__global__ __launch_bounds__(256) void merge_masks_kernel(
    const float* __restrict__ M, const int* __restrict__ mstart,
    const int* __restrict__ members, float* __restrict__ out_masks) {
  __shared__ float rows[8 * 256];
  __shared__ int msS[C + 1];
  __shared__ int memS[C];
  const int tid = threadIdx.x;
  const size_t p0 = (size_t)blockIdx.x * 8;

  msS[tid] = mstart[tid];
  if (tid == 0) msS[C] = mstart[C];
  memS[tid] = members[tid];

  const float4* src = reinterpret_cast<const float4*>(M + p0 * 256);
#pragma unroll
  for (int it = 0; it < 2; ++it)
    reinterpret_cast<float4*>(rows)[it * 256 + tid] = src[it * 256 + tid];
  __syncthreads();

  const int st = msS[tid], en = msS[tid + 1];
  float mx[8];
  if (en > st) {
    const int m0 = memS[st];
#pragma unroll
    for (int r = 0; r < 8; ++r) mx[r] = rows[r * 256 + m0];
    for (int k = st + 1; k < en; ++k) {
      const int mm = memS[k];
#pragma unroll
      for (int r = 0; r < 8; ++r) mx[r] = fmaxf(mx[r], rows[r * 256 + mm]);
    }
  } else {
#pragma unroll
    for (int r = 0; r < 8; ++r) mx[r] = 0.f;
  }
  __syncthreads();                 // reuse rows as output staging
#pragma unroll
  for (int r = 0; r < 8; ++r) rows[r * 256 + tid] = mx[r];
  __syncthreads();

  const int r2 = tid >> 6;
  const int cg = (tid & 63) << 2;
#pragma unroll
  for (int pass = 0; pass < 2; ++pass) {
    const int rr = pass * 4 + r2;
    floatx4 v = *reinterpret_cast<const floatx4*>(&rows[rr * 256 + cg]);
    __builtin_nontemporal_store(
        v, reinterpret_cast<floatx4*>(&out_masks[(p0 + rr) * 256 + cg]));
  }
}

// ---------------------------------------------------------------------------
// Kernel 6: new_cls[c][k] = valid(c) ? max over members of cls[j][k] : 0
// ---------------------------------------------------------------------------
__global__ __launch_bounds__(256) void merge_cls_kernel(
    const float* __restrict__ cls, const int* __restrict__ mstart,
    const int* __restrict__ members, float* __restrict__ out_cls) {
  __shared__ int se[2];
  const int c = blockIdx.x;
  const int t = threadIdx.x;
  if (t < 2) se[t] = mstart[c + t];
  __syncthreads();
  const int st = se[0], en = se[1];
  if (t < NC) {
    float mx = 0.f;
    if (en > st) {
      mx = cls[(size_t)members[st] * NC + t];
      for (int k = st + 1; k < en; ++k)
        mx = fmaxf(mx, cls[(size_t)members[k] * NC + t]);
    }
    out_cls[(size_t)c * NC + t] = mx;
  }
}

// ---------------------------------------------------------------------------
extern "C" void kernel_launch(void* const* d_in, const int* in_sizes, int n_in,
                              void* d_out, int out_size, void* d_ws,
                              size_t ws_size, hipStream_t stream) {
  const float* M = (const float*)d_in[0];    // [P, C] fp32
  const float* cls = (const float*)d_in[1];  // [C, NC] fp32

  float* out = (float*)d_out;
  char* ws = (char*)d_ws;
  float* G = (float*)(ws + WS_G);
  float* s = (float*)(ws + WS_S);
  float* p_row = (float*)(ws + WS_PROW);
  float* pT = (float*)(ws + WS_PT);
  unsigned long long* condW = (unsigned long long*)(ws + WS_COND);
  int* mstart = (int*)(ws + WS_MSTART);
  int* members = (int*)(ws + WS_MEMBERS);

  float* out_labels = out;
  float* out_valid = out + 256;
  float* out_masks = out + 512;
  float* out_cls = out + 512 + (size_t)P * 256;

  const bool bigws = ws_size >= WS_PART + PART_BYTES;
  float* part = bigws ? (float*)(ws + WS_PART) : nullptr;

  if (bigws) {
    hipMemsetAsync(ws + WS_S, 0, 1024, stream);       // s only; G overwritten
  } else {
    hipMemsetAsync(ws, 0, WS_S + 1024, stream);       // G + s (atomic path)
  }

  gram_mfma_kernel<<<dim3(3, NCHUNK), 256, 0, stream>>>(M, G, s, part);
  if (bigws) reduce_g_kernel<<<384, 128, 0, stream>>>(part, G);
  ln_kernel<<<C, 64, 0, stream>>>(cls, p_row, pT);
  cond_kernel<<<C, 256, 0, stream>>>(G, s, p_row, pT, condW);
  scan_kernel<<<1, 64, 0, stream>>>(condW, out_labels, out_valid, mstart,
                                    members);
  merge_masks_kernel<<<P / 8, 256, 0, stream>>>(M, mstart, members, out_masks);
  merge_cls_kernel<<<C, 256, 0, stream>>>(cls, mstart, members, out_cls);
}